// Round 6
// baseline (1545.413 us; speedup 1.0000x reference)
//
#include <hip/hip_runtime.h>
#include <math.h>

#define DEV __device__ __forceinline__

// ---------------- zero the fp32 output ----------------
__global__ __launch_bounds__(256) void k_init(unsigned int* __restrict__ out32, int n){
  int t = blockIdx.x * 256 + threadIdx.x;
  if (t < n) out32[t] = 0u;
}

// ---------------- repack conv_w[c][e][w] -> wT[e][w*512+c] ----------------
__global__ __launch_bounds__(256) void k_wT(const float* __restrict__ convw, float* __restrict__ wT){
  int t = blockIdx.x * 256 + threadIdx.x;      // < 300*2560 = 768000
  int e = t / 2560, wc = t - e * 2560;
  int w = wc >> 9, c = wc & 511;
  wT[t] = convw[(c * 300 + e) * 5 + w];
}

// ---------------- contrib[v][w*512+c] = sum_e emb[v][e]*convw[c][e][w]  (fp64 acc -> fp32) ----------------
__global__ __launch_bounds__(256) void k_contrib(const float* __restrict__ emb,
                                                 const float* __restrict__ wT,
                                                 float* __restrict__ contrib){
  __shared__ float aS[8][304];
  int tid = threadIdx.x;
  int v0 = blockIdx.x * 8;                      // 632 tiles -> v < 5056
  int wc = blockIdx.y * 256 + tid;              // 10 tiles -> 2560
  #pragma unroll
  for (int r = 0; r < 8; ++r){
    int v = v0 + r;
    for (int e = tid; e < 304; e += 256)
      aS[r][e] = (v < 5053 && e < 300) ? emb[(size_t)v * 300 + e] : 0.f;
  }
  __syncthreads();
  double p[8] = {0,0,0,0,0,0,0,0};
  for (int e = 0; e < 300; ++e){
    double b = (double)wT[(size_t)e * 2560 + wc];
    #pragma unroll
    for (int r = 0; r < 8; ++r) p[r] += (double)aS[r][e] * b;
  }
  #pragma unroll
  for (int r = 0; r < 8; ++r)
    contrib[(size_t)(v0 + r) * 2560 + wc] = (float)p[r];
}

// ---------------- char-CNN via contrib gather (fp64 math): one block per sequence ----------------
template<typename FT>
__global__ __launch_bounds__(256) void k_conv(const int* __restrict__ idx, int L,
                                              const float* __restrict__ contrib,
                                              const float* __restrict__ convb,
                                              FT* __restrict__ featAll, int row0){
  __shared__ int tok[512];
  __shared__ double red[256][4];
  int s = blockIdx.x, tid = threadIdx.x;
  const int* row = idx + (size_t)s * L;
  for (int i = tid; i < L; i += 256) tok[i] = row[i];
  __syncthreads();
  int c4 = tid & 127;                 // channel quad -> 512 channels
  int ph = tid >> 7;                  // position stripe 0/1
  double b0 = convb[c4 * 4 + 0], b1 = convb[c4 * 4 + 1];
  double b2 = convb[c4 * 4 + 2], b3 = convb[c4 * 4 + 3];
  double m0 = 0, m1 = 0, m2 = 0, m3 = 0;       // relu floor folded into init
  int P = L - 4;
  for (int p = ph; p < P; p += 2){
    double a0 = b0, a1 = b1, a2 = b2, a3 = b3;
    #pragma unroll
    for (int w = 0; w < 5; ++w){
      const float* vp = contrib + ((size_t)tok[p + w] * 5 + w) * 512 + c4 * 4;
      float4 v = *(const float4*)vp;
      a0 += (double)v.x; a1 += (double)v.y; a2 += (double)v.z; a3 += (double)v.w;
    }
    m0 = fmax(m0, a0); m1 = fmax(m1, a1); m2 = fmax(m2, a2); m3 = fmax(m3, a3);
  }
  red[tid][0] = m0; red[tid][1] = m1; red[tid][2] = m2; red[tid][3] = m3;
  __syncthreads();
  if (tid < 128){
    FT* o = featAll + (size_t)(row0 + s) * 512 + c4 * 4;
    o[0] = (FT)fmax(red[tid][0], red[tid + 128][0]);
    o[1] = (FT)fmax(red[tid][1], red[tid + 128][1]);
    o[2] = (FT)fmax(red[tid][2], red[tid + 128][2]);
    o[3] = (FT)fmax(red[tid][3], red[tid + 128][3]);
  }
}

// ---------------- repack Wih -> WihT[dir][k][col] ----------------
__global__ __launch_bounds__(256) void k_wihT(const float* __restrict__ Wf,
                                              const float* __restrict__ Wb,
                                              float* __restrict__ WihT){
  int t = blockIdx.x * 256 + threadIdx.x;      // < 2*512*512 = 524288
  int dir = t >> 18, r = t & 262143;
  int k = r >> 9, col = r & 511;
  WihT[t] = (dir ? Wb : Wf)[col * 512 + k];
}

// ---------------- input projection (fp64): preAll[dir][row][col] ----------------
template<typename FT>
__global__ __launch_bounds__(256) void k_proj(const FT* __restrict__ featAll,
                                              const float* __restrict__ WihT,
                                              const float* __restrict__ bihF, const float* __restrict__ bhhF,
                                              const float* __restrict__ bihB, const float* __restrict__ bhhB,
                                              double* __restrict__ preAll){
  __shared__ FT aS[8][520];
  int tid = threadIdx.x;
  int v0 = blockIdx.x * 8;                     // 522 tiles -> rows < 4176
  int col = blockIdx.y * 256 + tid;            // 2 tiles -> 512
  int dir = blockIdx.z;
  #pragma unroll
  for (int r = 0; r < 8; ++r)
    for (int k = tid; k < 520; k += 256)
      aS[r][k] = (k < 512) ? featAll[(size_t)(v0 + r) * 512 + k] : (FT)0;
  __syncthreads();
  const float* BT = WihT + (size_t)dir * 262144;
  double acc[8] = {0,0,0,0,0,0,0,0};
  for (int k = 0; k < 512; ++k){
    double b = (double)BT[(size_t)k * 512 + col];
    #pragma unroll
    for (int r = 0; r < 8; ++r)
      acc[r] += (double)aS[r][k] * b;
  }
  double bias = (double)(dir ? bihB : bihF)[col] + (double)(dir ? bhhB : bhhF)[col];
  double* outp = preAll + (size_t)dir * 4176 * 512;
  #pragma unroll
  for (int r = 0; r < 8; ++r)
    outp[(size_t)(v0 + r) * 512 + col] = acc[r] + bias;
}

// ---------------- LSTM recurrence (fp64): block = one (chain, dir); 512 threads ----------------
__global__ __launch_bounds__(512) void k_recur(const double* __restrict__ preAll,
                                               const float* __restrict__ WhhF,
                                               const float* __restrict__ WhhB,
                                               const int* __restrict__ cand,
                                               double* __restrict__ hT, double* __restrict__ hB,
                                               double* __restrict__ hC, double* __restrict__ hD){
  int c = blockIdx.x, dir = blockIdx.y, tid = threadIdx.x;
  int lstm = (c < 64) ? 0 : (c < 128) ? 1 : (c < 192) ? 2 : 3;
  int b = (lstm == 3) ? 0 : (c - lstm * 64);
  const float* Whh = dir ? WhhB : WhhF;
  const double* pre = preAll + (size_t)dir * 4176 * 512;
  double* hout;
  if (lstm == 0)      hout = hT + (size_t)b * 32 * 256;
  else if (lstm == 1) hout = hB + (size_t)b * 32 * 256;
  else if (lstm == 2) hout = hC + (size_t)b * 32 * 256;
  else                hout = hD;
  hout += dir * 128;

  float wr[128];                                // this gate row of Whh
  #pragma unroll
  for (int i = 0; i < 128; ++i) wr[i] = Whh[(size_t)tid * 128 + i];

  __shared__ double hs[128];
  __shared__ double gd[512];
  __shared__ int candL[32];
  if (tid < 128) hs[tid] = 0.0;
  if (lstm < 2 && tid < 32) candL[tid] = cand[b * 32 + tid];
  __syncthreads();
  double cst = 0.0;
  for (int s = 0; s < 32; ++s){
    int t = dir ? (31 - s) : s;
    int rowi;
    if (lstm == 0)      rowi = candL[t];
    else if (lstm == 1) rowi = 2048 + candL[t];
    else if (lstm == 2) rowi = 4096 + b;
    else                rowi = 4160;
    double g = pre[(size_t)rowi * 512 + tid];
    #pragma unroll
    for (int j = 0; j < 128; ++j)
      g += (double)wr[j] * hs[j];
    gd[tid] = g;
    __syncthreads();
    if (tid < 128){
      double gi = gd[tid], gf = gd[tid + 128], gg = gd[tid + 256], go = gd[tid + 384];
      double si = 1.0 / (1.0 + exp(-gi));
      double sf = 1.0 / (1.0 + exp(-gf));
      double so = 1.0 / (1.0 + exp(-go));
      cst = sf * cst + si * tanh(gg);
      double h = so * tanh(cst);
      hs[tid] = h;
      hout[(size_t)t * 256 + tid] = h;
    }
    __syncthreads();
  }
}

// ---------------- BiDAF attention + scoring + scatter (fp64): one block per mention ----------------
__global__ __launch_bounds__(256) void k_att(const double* __restrict__ hC,
                                             const double* __restrict__ hT,
                                             const double* __restrict__ hD,
                                             const double* __restrict__ hB,
                                             const float* __restrict__ wc_g, const float* __restrict__ bc_g,
                                             const float* __restrict__ wq_g, const float* __restrict__ bq_g,
                                             const float* __restrict__ wcq_g, const float* __restrict__ bcq_g,
                                             const float* __restrict__ wz_g, const float* __restrict__ bz_g,
                                             const float* __restrict__ wp1_g, const float* __restrict__ bp1_g,
                                             const float* __restrict__ wp2_g, const float* __restrict__ bp2_g,
                                             const int* __restrict__ cand,
                                             float* __restrict__ out){
  int b = blockIdx.x, tid = threadIdx.x;
  __shared__ double sD[32][33];
  __shared__ double tD[32][33];
  __shared__ double cwS[32], qwS[32], qzS[32], smaxS[32], bsmS[32];
  __shared__ double q2cS[256];
  __shared__ double p1S[32], p2S[32], scoreS[32], redS[3];
  double bsum = (double)bc_g[0] + (double)bq_g[0] + (double)bcq_g[0];
  double bzv = (double)bz_g[0];
  double pa = 0.0;
  for (int pass = 0; pass < 2; ++pass){
    const double* cp = pass ? hD : (hC + (size_t)b * 8192);
    const double* qp = (pass ? hB : hT) + (size_t)b * 8192;
    if (tid < 32){
      double a = 0;
      for (int d = 0; d < 256; ++d) a += cp[(size_t)tid * 256 + d] * (double)wc_g[d];
      cwS[tid] = a;
    } else if (tid < 64){
      int j = tid - 32; double a = 0;
      for (int d = 0; d < 256; ++d) a += qp[(size_t)j * 256 + d] * (double)wq_g[d];
      qwS[j] = a;
    } else if (tid < 96){
      int j = tid - 64; double a = 0;
      for (int d = 0; d < 256; ++d) a += qp[(size_t)j * 256 + d] * (double)wz_g[256 + d];
      qzS[j] = a;
    }
    {
      int i = tid >> 3, js = tid & 7;
      double sa[4] = {0,0,0,0}, ta[4] = {0,0,0,0};
      for (int d = 0; d < 256; ++d){
        double cd = cp[(size_t)i * 256 + d];
        double cw1 = cd * (double)wcq_g[d];
        double cw2 = cd * (double)wz_g[512 + d];
        #pragma unroll
        for (int m = 0; m < 4; ++m){
          double qv = qp[(size_t)(js + m * 8) * 256 + d];
          sa[m] += cw1 * qv;
          ta[m] += cw2 * qv;
        }
      }
      __syncthreads();   // cwS/qwS/qzS ready; also protects sD/tD reuse across passes
      #pragma unroll
      for (int m = 0; m < 4; ++m){
        int j = js + m * 8;
        sD[i][j] = sa[m] + cwS[i] + qwS[j] + bsum;
        tD[i][j] = ta[m];
      }
    }
    __syncthreads();
    if (tid < 32){
      int i = tid;
      double mx = sD[i][0];
      for (int j = 1; j < 32; ++j) mx = fmax(mx, sD[i][j]);
      smaxS[i] = mx;
      double sum = 0, acc = 0;
      for (int j = 0; j < 32; ++j){
        double e = exp(sD[i][j] - mx);
        sum += e;
        acc += e * (qzS[j] + tD[i][j]);
      }
      pa = acc / sum;   // c2q + c*c2q terms folded
    }
    __syncthreads();
    if (tid == 0){
      double mx = smaxS[0];
      for (int i = 1; i < 32; ++i) mx = fmax(mx, smaxS[i]);
      double sum = 0, e_[32];
      for (int i = 0; i < 32; ++i){ e_[i] = exp(smaxS[i] - mx); sum += e_[i]; }
      double inv = 1.0 / sum;
      for (int i = 0; i < 32; ++i) bsmS[i] = e_[i] * inv;
    }
    __syncthreads();
    {
      double a = 0;
      for (int i = 0; i < 32; ++i) a += bsmS[i] * cp[(size_t)i * 256 + tid];
      q2cS[tid] = a;
    }
    __syncthreads();
    if (tid < 32){
      int i = tid; double t1 = 0, t4 = 0;
      for (int d = 0; d < 256; ++d){
        double cd = cp[(size_t)i * 256 + d];
        t1 += cd * (double)wz_g[d];
        t4 += cd * q2cS[d] * (double)wz_g[768 + d];
      }
      double pv = t1 + pa + t4 + bzv;
      if (pass) p2S[i] = pv; else p1S[i] = pv;
    }
    __syncthreads();
  }
  if (tid < 32)
    scoreS[tid] = (double)wp1_g[0] * p1S[tid] + (double)bp1_g[0]
                + (double)wp2_g[0] * p2S[tid] + (double)bp2_g[0];
  __syncthreads();
  if (tid == 0){
    double mx = scoreS[0];
    for (int i = 1; i < 32; ++i) mx = fmax(mx, scoreS[i]);
    double es = 0, rs = 0;
    for (int i = 0; i < 32; ++i){ es += exp(scoreS[i] - mx); rs += scoreS[i]; }
    redS[0] = mx; redS[1] = es; redS[2] = rs;
  }
  __syncthreads();
  if (tid < 32){
    int col = cand[b * 32 + tid];
    double sc = scoreS[tid];
    out[(size_t)b * 2048 + col] = (float)sc;                                  // score
    out[131072 + (size_t)b * 2048 + col] = (float)(exp(sc - redS[0]) / redS[1]); // softmax
    out[262144 + (size_t)b * 2048 + col] = (float)(sc / redS[2]);             // sum-normalized
  }
}

// ---------------------------------------------------------------------------
extern "C" void kernel_launch(void* const* d_in, const int* in_sizes, int n_in,
                              void* d_out, int out_size, void* d_ws, size_t ws_size,
                              hipStream_t stream) {
  const int* title_v = (const int*)d_in[0];
  const int* body_v  = (const int*)d_in[1];
  // d_in[2] = mention_vec (unused by the reference)
  const int* ctx_v   = (const int*)d_in[3];
  const int* doc_v   = (const int*)d_in[4];
  const int* cand    = (const int*)d_in[5];
  const float* emb   = (const float*)d_in[6];
  const float* convw = (const float*)d_in[7];
  const float* convb = (const float*)d_in[8];
  const float* WihF  = (const float*)d_in[9];
  const float* WhhF  = (const float*)d_in[10];
  const float* bihF  = (const float*)d_in[11];
  const float* bhhF  = (const float*)d_in[12];
  const float* WihB  = (const float*)d_in[13];
  const float* WhhB  = (const float*)d_in[14];
  const float* bihB  = (const float*)d_in[15];
  const float* bhhB  = (const float*)d_in[16];
  float* out = (float*)d_out;          // reference outputs are float32

  const size_t CONTRIB_B = (size_t)5056 * 2560 * 4;     // 51,773,440
  const size_t FEATF_B   = (size_t)4176 * 512 * 4;      //  8,552,448
  const size_t FEATD_B   = (size_t)4176 * 512 * 8;      // 17,104,896
  char* base = (char*)d_ws;
  float* contrib = (float*)base;
  char* featBase = base + CONTRIB_B;
  bool featDouble = (ws_size >= CONTRIB_B + FEATD_B);
  size_t featB = featDouble ? FEATD_B : FEATF_B;
  if (ws_size < CONTRIB_B + featB) return;              // -> all-zero output (diagnosable)
  float* wT = (float*)featBase;                         // dead before k_conv writes feat

  // Aliases inside contrib (dead after k_conv); all 256-aligned.
  float*  WihT   = (float*)(base);                      // 2,097,152 B
  double* preAll = (double*)(base + 2097152);           // 34,209,792 B -> ends 36,306,944
  double* hT     = (double*)(base + 36306944);          // 4,194,304 B
  double* hB     = (double*)(base + 40501248);
  double* hC     = (double*)(base + 44695552);
  double* hD     = (double*)(base + 48889856);          // 65,536 B -> ends 48,955,392 < 51,773,440

  k_init<<<(out_size + 255) / 256, 256, 0, stream>>>((unsigned int*)out, out_size);
  k_wT<<<3000, 256, 0, stream>>>(convw, wT);
  k_contrib<<<dim3(632, 10), 256, 0, stream>>>(emb, wT, contrib);

  if (featDouble){
    double* feat = (double*)featBase;
    k_conv<double><<<2048, 256, 0, stream>>>(title_v, 32, contrib, convb, feat, 0);
    k_conv<double><<<2048, 256, 0, stream>>>(body_v, 128, contrib, convb, feat, 2048);
    k_conv<double><<<64, 256, 0, stream>>>(ctx_v, 128, contrib, convb, feat, 4096);
    k_conv<double><<<1, 256, 0, stream>>>(doc_v, 512, contrib, convb, feat, 4160);
    k_wihT<<<2048, 256, 0, stream>>>(WihF, WihB, WihT);
    k_proj<double><<<dim3(522, 2, 2), 256, 0, stream>>>(feat, WihT, bihF, bhhF, bihB, bhhB, preAll);
  } else {
    float* feat = (float*)featBase;
    k_conv<float><<<2048, 256, 0, stream>>>(title_v, 32, contrib, convb, feat, 0);
    k_conv<float><<<2048, 256, 0, stream>>>(body_v, 128, contrib, convb, feat, 2048);
    k_conv<float><<<64, 256, 0, stream>>>(ctx_v, 128, contrib, convb, feat, 4096);
    k_conv<float><<<1, 256, 0, stream>>>(doc_v, 512, contrib, convb, feat, 4160);
    k_wihT<<<2048, 256, 0, stream>>>(WihF, WihB, WihT);
    k_proj<float><<<dim3(522, 2, 2), 256, 0, stream>>>(feat, WihT, bihF, bhhF, bihB, bhhB, preAll);
  }

  k_recur<<<dim3(193, 2), 512, 0, stream>>>(preAll, WhhF, WhhB, cand, hT, hB, hC, hD);
  k_att<<<64, 256, 0, stream>>>(hC, hT, hD, hB,
                                (const float*)d_in[17], (const float*)d_in[18],
                                (const float*)d_in[19], (const float*)d_in[20],
                                (const float*)d_in[21], (const float*)d_in[22],
                                (const float*)d_in[23], (const float*)d_in[24],
                                (const float*)d_in[25], (const float*)d_in[26],
                                (const float*)d_in[27], (const float*)d_in[28],
                                cand, out);
}

// Round 7
// 1398.317 us; speedup vs baseline: 1.1052x; 1.1052x over previous
//
#include <hip/hip_runtime.h>
#include <math.h>

// ---------------- zero the fp32 output ----------------
__global__ __launch_bounds__(256) void k_init(unsigned int* __restrict__ out32, int n){
  int t = blockIdx.x * 256 + threadIdx.x;
  if (t < n) out32[t] = 0u;
}

// ---------------- repack conv_w[c][e][w] -> wT[e][w*512+c] ----------------
__global__ __launch_bounds__(256) void k_wT(const float* __restrict__ convw, float* __restrict__ wT){
  int t = blockIdx.x * 256 + threadIdx.x;      // < 300*2560 = 768000
  int e = t / 2560, wc = t - e * 2560;
  int w = wc >> 9, c = wc & 511;
  wT[t] = convw[(c * 300 + e) * 5 + w];
}

// ---------------- contrib[v][w*512+c] = sum_e emb[v][e]*convw[c][e][w]  (fp32, 2 cols/thread) ----------------
__global__ __launch_bounds__(256) void k_contrib(const float* __restrict__ emb,
                                                 const float* __restrict__ wT,
                                                 float* __restrict__ contrib){
  __shared__ float aS[8][304];                  // row stride 1216 B (16B-aligned)
  int tid = threadIdx.x;
  int v0 = blockIdx.x * 8;                      // 632 tiles -> v < 5056
  int wc0 = blockIdx.y * 256 + tid;             // 5 tiles -> cols [0,1280)
  int wc1 = wc0 + 1280;                         // second col stripe
  #pragma unroll
  for (int r = 0; r < 8; ++r){
    int v = v0 + r;
    for (int e = tid; e < 304; e += 256)
      aS[r][e] = (v < 5053 && e < 300) ? emb[(size_t)v * 300 + e] : 0.f;
  }
  __syncthreads();
  float acc0[8] = {0,0,0,0,0,0,0,0}, acc1[8] = {0,0,0,0,0,0,0,0};
  for (int e = 0; e < 300; e += 4){
    float b00 = wT[(size_t)(e + 0) * 2560 + wc0];
    float b01 = wT[(size_t)(e + 1) * 2560 + wc0];
    float b02 = wT[(size_t)(e + 2) * 2560 + wc0];
    float b03 = wT[(size_t)(e + 3) * 2560 + wc0];
    float b10 = wT[(size_t)(e + 0) * 2560 + wc1];
    float b11 = wT[(size_t)(e + 1) * 2560 + wc1];
    float b12 = wT[(size_t)(e + 2) * 2560 + wc1];
    float b13 = wT[(size_t)(e + 3) * 2560 + wc1];
    #pragma unroll
    for (int r = 0; r < 8; ++r){
      float4 a = *(const float4*)&aS[r][e];
      acc0[r] += a.x * b00 + a.y * b01 + a.z * b02 + a.w * b03;
      acc1[r] += a.x * b10 + a.y * b11 + a.z * b12 + a.w * b13;
    }
  }
  #pragma unroll
  for (int r = 0; r < 8; ++r){
    contrib[(size_t)(v0 + r) * 2560 + wc0] = acc0[r];
    contrib[(size_t)(v0 + r) * 2560 + wc1] = acc1[r];
  }
}

// ---------------- char-CNN via contrib gather (fp32): one block per sequence ----------------
__global__ __launch_bounds__(256) void k_conv(const int* __restrict__ idx, int L,
                                              const float* __restrict__ contrib,
                                              const float* __restrict__ convb,
                                              float* __restrict__ featAll, int row0){
  __shared__ int tok[512];
  __shared__ float4 red[256];
  int s = blockIdx.x, tid = threadIdx.x;
  const int* row = idx + (size_t)s * L;
  for (int i = tid; i < L; i += 256) tok[i] = row[i];
  __syncthreads();
  int c4 = tid & 127;                 // channel quad -> 512 channels
  int ph = tid >> 7;                  // position stripe 0/1
  float4 bias = *(const float4*)(convb + c4 * 4);
  float4 mx = {0.f, 0.f, 0.f, 0.f};   // relu floor folded into init
  int P = L - 4;
  for (int p = ph; p < P; p += 2){
    float4 acc = bias;
    #pragma unroll
    for (int w = 0; w < 5; ++w){
      float4 v = *(const float4*)(contrib + ((size_t)tok[p + w] * 5 + w) * 512 + c4 * 4);
      acc.x += v.x; acc.y += v.y; acc.z += v.z; acc.w += v.w;
    }
    mx.x = fmaxf(mx.x, acc.x); mx.y = fmaxf(mx.y, acc.y);
    mx.z = fmaxf(mx.z, acc.z); mx.w = fmaxf(mx.w, acc.w);
  }
  red[tid] = mx;
  __syncthreads();
  if (tid < 128){
    float4 a = red[tid], bb = red[tid + 128];
    a.x = fmaxf(a.x, bb.x); a.y = fmaxf(a.y, bb.y);
    a.z = fmaxf(a.z, bb.z); a.w = fmaxf(a.w, bb.w);
    *(float4*)(featAll + (size_t)(row0 + s) * 512 + c4 * 4) = a;
  }
}

// ---------------- repack Wih -> WihT[dir][k][col] ----------------
__global__ __launch_bounds__(256) void k_wihT(const float* __restrict__ Wf,
                                              const float* __restrict__ Wb,
                                              float* __restrict__ WihT){
  int t = blockIdx.x * 256 + threadIdx.x;      // < 2*512*512 = 524288
  int dir = t >> 18, r = t & 262143;
  int k = r >> 9, col = r & 511;
  WihT[t] = (dir ? Wb : Wf)[col * 512 + k];
}

// ---------------- input projection (fp32, 2 cols/thread): preAll[dir][row][col] ----------------
__global__ __launch_bounds__(256) void k_proj(const float* __restrict__ featAll,
                                              const float* __restrict__ WihT,
                                              const float* __restrict__ bihF, const float* __restrict__ bhhF,
                                              const float* __restrict__ bihB, const float* __restrict__ bhhB,
                                              float* __restrict__ preAll){
  __shared__ float aS[8][516];                 // row stride 2064 B (16B-aligned)
  int tid = threadIdx.x;
  int v0 = blockIdx.x * 8;                     // 522 tiles -> rows < 4176
  int dir = blockIdx.z;
  int col0 = tid, col1 = tid + 256;
  #pragma unroll
  for (int r = 0; r < 8; ++r)
    for (int k = tid; k < 516; k += 256)
      aS[r][k] = (k < 512) ? featAll[(size_t)(v0 + r) * 512 + k] : 0.f;
  __syncthreads();
  const float* BT = WihT + (size_t)dir * 262144;
  float acc0[8] = {0,0,0,0,0,0,0,0}, acc1[8] = {0,0,0,0,0,0,0,0};
  for (int k = 0; k < 512; k += 4){
    float b00 = BT[(size_t)(k + 0) * 512 + col0];
    float b01 = BT[(size_t)(k + 1) * 512 + col0];
    float b02 = BT[(size_t)(k + 2) * 512 + col0];
    float b03 = BT[(size_t)(k + 3) * 512 + col0];
    float b10 = BT[(size_t)(k + 0) * 512 + col1];
    float b11 = BT[(size_t)(k + 1) * 512 + col1];
    float b12 = BT[(size_t)(k + 2) * 512 + col1];
    float b13 = BT[(size_t)(k + 3) * 512 + col1];
    #pragma unroll
    for (int r = 0; r < 8; ++r){
      float4 a = *(const float4*)&aS[r][k];
      acc0[r] += a.x * b00 + a.y * b01 + a.z * b02 + a.w * b03;
      acc1[r] += a.x * b10 + a.y * b11 + a.z * b12 + a.w * b13;
    }
  }
  float bias0 = (dir ? bihB : bihF)[col0] + (dir ? bhhB : bhhF)[col0];
  float bias1 = (dir ? bihB : bihF)[col1] + (dir ? bhhB : bhhF)[col1];
  float* outp = preAll + (size_t)dir * 4176 * 512;
  #pragma unroll
  for (int r = 0; r < 8; ++r){
    outp[(size_t)(v0 + r) * 512 + col0] = acc0[r] + bias0;
    outp[(size_t)(v0 + r) * 512 + col1] = acc1[r] + bias1;
  }
}

// ---------------- LSTM recurrence (fp64): block = one (chain, dir); 512 threads ----------------
__global__ __launch_bounds__(512) void k_recur(const float* __restrict__ preAll,
                                               const float* __restrict__ WhhF,
                                               const float* __restrict__ WhhB,
                                               const int* __restrict__ cand,
                                               double* __restrict__ hT, double* __restrict__ hB,
                                               double* __restrict__ hC, double* __restrict__ hD){
  int c = blockIdx.x, dir = blockIdx.y, tid = threadIdx.x;
  int lstm = (c < 64) ? 0 : (c < 128) ? 1 : (c < 192) ? 2 : 3;
  int b = (lstm == 3) ? 0 : (c - lstm * 64);
  const float* Whh = dir ? WhhB : WhhF;
  const float* pre = preAll + (size_t)dir * 4176 * 512;
  double* hout;
  if (lstm == 0)      hout = hT + (size_t)b * 32 * 256;
  else if (lstm == 1) hout = hB + (size_t)b * 32 * 256;
  else if (lstm == 2) hout = hC + (size_t)b * 32 * 256;
  else                hout = hD;
  hout += dir * 128;

  float wr[128];                                // this gate row of Whh
  #pragma unroll
  for (int i = 0; i < 128; ++i) wr[i] = Whh[(size_t)tid * 128 + i];

  __shared__ double hs[128];
  __shared__ double gd[512];
  __shared__ int candL[32];
  if (tid < 128) hs[tid] = 0.0;
  if (lstm < 2 && tid < 32) candL[tid] = cand[b * 32 + tid];
  __syncthreads();
  double cst = 0.0;
  for (int s = 0; s < 32; ++s){
    int t = dir ? (31 - s) : s;
    int rowi;
    if (lstm == 0)      rowi = candL[t];
    else if (lstm == 1) rowi = 2048 + candL[t];
    else if (lstm == 2) rowi = 4096 + b;
    else                rowi = 4160;
    double g = (double)pre[(size_t)rowi * 512 + tid];
    #pragma unroll
    for (int j = 0; j < 128; ++j)
      g += (double)wr[j] * hs[j];
    gd[tid] = g;
    __syncthreads();
    if (tid < 128){
      double gi = gd[tid], gf = gd[tid + 128], gg = gd[tid + 256], go = gd[tid + 384];
      double si = 1.0 / (1.0 + exp(-gi));
      double sf = 1.0 / (1.0 + exp(-gf));
      double so = 1.0 / (1.0 + exp(-go));
      cst = sf * cst + si * tanh(gg);
      double h = so * tanh(cst);
      hs[tid] = h;
      hout[(size_t)t * 256 + tid] = h;
    }
    __syncthreads();
  }
}

// ---------------- BiDAF attention + scoring + scatter (fp64): one block per mention ----------------
__global__ __launch_bounds__(256) void k_att(const double* __restrict__ hC,
                                             const double* __restrict__ hT,
                                             const double* __restrict__ hD,
                                             const double* __restrict__ hB,
                                             const float* __restrict__ wc_g, const float* __restrict__ bc_g,
                                             const float* __restrict__ wq_g, const float* __restrict__ bq_g,
                                             const float* __restrict__ wcq_g, const float* __restrict__ bcq_g,
                                             const float* __restrict__ wz_g, const float* __restrict__ bz_g,
                                             const float* __restrict__ wp1_g, const float* __restrict__ bp1_g,
                                             const float* __restrict__ wp2_g, const float* __restrict__ bp2_g,
                                             const int* __restrict__ cand,
                                             float* __restrict__ out){
  int b = blockIdx.x, tid = threadIdx.x;
  __shared__ double sD[32][33];
  __shared__ double tD[32][33];
  __shared__ double cwS[32], qwS[32], qzS[32], smaxS[32], bsmS[32];
  __shared__ double q2cS[256];
  __shared__ double p1S[32], p2S[32], scoreS[32], redS[3];
  double bsum = (double)bc_g[0] + (double)bq_g[0] + (double)bcq_g[0];
  double bzv = (double)bz_g[0];
  double pa = 0.0;
  for (int pass = 0; pass < 2; ++pass){
    const double* cp = pass ? hD : (hC + (size_t)b * 8192);
    const double* qp = (pass ? hB : hT) + (size_t)b * 8192;
    if (tid < 32){
      double a = 0;
      for (int d = 0; d < 256; ++d) a += cp[(size_t)tid * 256 + d] * (double)wc_g[d];
      cwS[tid] = a;
    } else if (tid < 64){
      int j = tid - 32; double a = 0;
      for (int d = 0; d < 256; ++d) a += qp[(size_t)j * 256 + d] * (double)wq_g[d];
      qwS[j] = a;
    } else if (tid < 96){
      int j = tid - 64; double a = 0;
      for (int d = 0; d < 256; ++d) a += qp[(size_t)j * 256 + d] * (double)wz_g[256 + d];
      qzS[j] = a;
    }
    {
      int i = tid >> 3, js = tid & 7;
      double sa[4] = {0,0,0,0}, ta[4] = {0,0,0,0};
      for (int d = 0; d < 256; ++d){
        double cd = cp[(size_t)i * 256 + d];
        double cw1 = cd * (double)wcq_g[d];
        double cw2 = cd * (double)wz_g[512 + d];
        #pragma unroll
        for (int m = 0; m < 4; ++m){
          double qv = qp[(size_t)(js + m * 8) * 256 + d];
          sa[m] += cw1 * qv;
          ta[m] += cw2 * qv;
        }
      }
      __syncthreads();   // cwS/qwS/qzS ready; also protects sD/tD reuse across passes
      #pragma unroll
      for (int m = 0; m < 4; ++m){
        int j = js + m * 8;
        sD[i][j] = sa[m] + cwS[i] + qwS[j] + bsum;
        tD[i][j] = ta[m];
      }
    }
    __syncthreads();
    if (tid < 32){
      int i = tid;
      double mx = sD[i][0];
      for (int j = 1; j < 32; ++j) mx = fmax(mx, sD[i][j]);
      smaxS[i] = mx;
      double sum = 0, acc = 0;
      for (int j = 0; j < 32; ++j){
        double e = exp(sD[i][j] - mx);
        sum += e;
        acc += e * (qzS[j] + tD[i][j]);
      }
      pa = acc / sum;   // c2q + c*c2q terms folded
    }
    __syncthreads();
    if (tid == 0){
      double mx = smaxS[0];
      for (int i = 1; i < 32; ++i) mx = fmax(mx, smaxS[i]);
      double sum = 0, e_[32];
      for (int i = 0; i < 32; ++i){ e_[i] = exp(smaxS[i] - mx); sum += e_[i]; }
      double inv = 1.0 / sum;
      for (int i = 0; i < 32; ++i) bsmS[i] = e_[i] * inv;
    }
    __syncthreads();
    {
      double a = 0;
      for (int i = 0; i < 32; ++i) a += bsmS[i] * cp[(size_t)i * 256 + tid];
      q2cS[tid] = a;
    }
    __syncthreads();
    if (tid < 32){
      int i = tid; double t1 = 0, t4 = 0;
      for (int d = 0; d < 256; ++d){
        double cd = cp[(size_t)i * 256 + d];
        t1 += cd * (double)wz_g[d];
        t4 += cd * q2cS[d] * (double)wz_g[768 + d];
      }
      double pv = t1 + pa + t4 + bzv;
      if (pass) p2S[i] = pv; else p1S[i] = pv;
    }
    __syncthreads();
  }
  if (tid < 32)
    scoreS[tid] = (double)wp1_g[0] * p1S[tid] + (double)bp1_g[0]
                + (double)wp2_g[0] * p2S[tid] + (double)bp2_g[0];
  __syncthreads();
  if (tid == 0){
    double mx = scoreS[0];
    for (int i = 1; i < 32; ++i) mx = fmax(mx, scoreS[i]);
    double es = 0, rs = 0;
    for (int i = 0; i < 32; ++i){ es += exp(scoreS[i] - mx); rs += scoreS[i]; }
    redS[0] = mx; redS[1] = es; redS[2] = rs;
  }
  __syncthreads();
  if (tid < 32){
    int col = cand[b * 32 + tid];
    double sc = scoreS[tid];
    out[(size_t)b * 2048 + col] = (float)sc;                                  // score
    out[131072 + (size_t)b * 2048 + col] = (float)(exp(sc - redS[0]) / redS[1]); // softmax
    out[262144 + (size_t)b * 2048 + col] = (float)(sc / redS[2]);             // sum-normalized
  }
}

// ---------------------------------------------------------------------------
extern "C" void kernel_launch(void* const* d_in, const int* in_sizes, int n_in,
                              void* d_out, int out_size, void* d_ws, size_t ws_size,
                              hipStream_t stream) {
  const int* title_v = (const int*)d_in[0];
  const int* body_v  = (const int*)d_in[1];
  // d_in[2] = mention_vec (unused by the reference)
  const int* ctx_v   = (const int*)d_in[3];
  const int* doc_v   = (const int*)d_in[4];
  const int* cand    = (const int*)d_in[5];
  const float* emb   = (const float*)d_in[6];
  const float* convw = (const float*)d_in[7];
  const float* convb = (const float*)d_in[8];
  const float* WihF  = (const float*)d_in[9];
  const float* WhhF  = (const float*)d_in[10];
  const float* bihF  = (const float*)d_in[11];
  const float* bhhF  = (const float*)d_in[12];
  const float* WihB  = (const float*)d_in[13];
  const float* WhhB  = (const float*)d_in[14];
  const float* bihB  = (const float*)d_in[15];
  const float* bhhB  = (const float*)d_in[16];
  float* out = (float*)d_out;          // reference outputs are float32

  const size_t CONTRIB_B = (size_t)5056 * 2560 * 4;     // 51,773,440
  const size_t FEAT_B    = (size_t)4176 * 512 * 4;      //  8,552,448
  char* base = (char*)d_ws;
  float* contrib = (float*)base;
  char* featBase = base + CONTRIB_B;
  if (ws_size < CONTRIB_B + FEAT_B) return;             // -> all-zero output (diagnosable)
  float* wT   = (float*)featBase;                       // dead before k_conv writes feat
  float* feat = (float*)featBase;

  // Aliases inside contrib (dead after k_conv); all 256-aligned.
  float*  WihT   = (float*)(base);                      //  2,097,152 B
  float*  preAll = (float*)(base + 2097152);            // 17,104,896 B -> ends 19,202,048
  double* hT     = (double*)(base + 19202048);          //  4,194,304 B
  double* hB     = (double*)(base + 23396352);
  double* hC     = (double*)(base + 27590656);
  double* hD     = (double*)(base + 31784960);          // 65,536 B -> ends 31,850,496 < 51,773,440

  k_init<<<(out_size + 255) / 256, 256, 0, stream>>>((unsigned int*)out, out_size);
  k_wT<<<3000, 256, 0, stream>>>(convw, wT);
  k_contrib<<<dim3(632, 5), 256, 0, stream>>>(emb, wT, contrib);

  k_conv<<<2048, 256, 0, stream>>>(title_v, 32, contrib, convb, feat, 0);
  k_conv<<<2048, 256, 0, stream>>>(body_v, 128, contrib, convb, feat, 2048);
  k_conv<<<64, 256, 0, stream>>>(ctx_v, 128, contrib, convb, feat, 4096);
  k_conv<<<1, 256, 0, stream>>>(doc_v, 512, contrib, convb, feat, 4160);
  // WihT/preAll alias contrib -> launched after all k_conv (stream-ordered)
  k_wihT<<<2048, 256, 0, stream>>>(WihF, WihB, WihT);
  k_proj<<<dim3(522, 1, 2), 256, 0, stream>>>(feat, WihT, bihF, bhhF, bihB, bhhB, preAll);
  k_recur<<<dim3(193, 2), 512, 0, stream>>>(preAll, WhhF, WhhB, cand, hT, hB, hC, hD);
  k_att<<<64, 256, 0, stream>>>(hC, hT, hD, hB,
                                (const float*)d_in[17], (const float*)d_in[18],
                                (const float*)d_in[19], (const float*)d_in[20],
                                (const float*)d_in[21], (const float*)d_in[22],
                                (const float*)d_in[23], (const float*)d_in[24],
                                (const float*)d_in[25], (const float*)d_in[26],
                                (const float*)d_in[27], (const float*)d_in[28],
                                cand, out);
}

// Round 8
// 1177.472 us; speedup vs baseline: 1.3125x; 1.1876x over previous
//
#include <hip/hip_runtime.h>
#include <math.h>

// ---- ws layout (bytes) ----
// contrib: [0, 51,773,440) as [v<5056][w*512+c] fp32; rows v>=5053 never read -> "hole"
//   hole @ 51,742,720: flags[2048] (+0), nUsed (+8192), list[2048] (+8448)
// feat: [51,773,440, +8,552,448)  (wT occupies its first 3 MB before convs)
// post-conv aliases inside contrib: WihT @0, preAll @2,097,152, hT/hB/hC/hD @19,202,048..
#define HOLE_B 51742720ULL

// ---------------- init: zero output + dedup flags + doc feat row ----------------
__global__ __launch_bounds__(256) void k_init(unsigned int* __restrict__ out32, int n,
                                              unsigned int* __restrict__ hole32,
                                              float* __restrict__ featDoc){
  int t = blockIdx.x * 256 + threadIdx.x;
  if (t < n) out32[t] = 0u;
  if (t < 2112) hole32[t] = 0u;          // flags + nUsed (+pad)
  if (t < 512) featDoc[t] = 0.f;         // atomicMax target (relu floor 0)
}

// ---------------- mark used entities ----------------
__global__ __launch_bounds__(256) void k_mark(const int* __restrict__ cand, int* __restrict__ flags){
  int t = blockIdx.x * 256 + threadIdx.x;     // 2048 threads
  flags[cand[t]] = 1;
}

// ---------------- compact used entities into list ----------------
__global__ __launch_bounds__(256) void k_compact(const int* __restrict__ flags,
                                                 int* __restrict__ nUsed, int* __restrict__ list){
  int t = blockIdx.x * 256 + threadIdx.x;     // 2048 threads
  if (flags[t]){
    int s = atomicAdd(nUsed, 1);
    list[s] = t;
  }
}

// ---------------- repack conv_w[c][e][w] -> wT[e][w*512+c] ----------------
__global__ __launch_bounds__(256) void k_wT(const float* __restrict__ convw, float* __restrict__ wT){
  int t = blockIdx.x * 256 + threadIdx.x;      // < 300*2560 = 768000
  int e = t / 2560, wc = t - e * 2560;
  int w = wc >> 9, c = wc & 511;
  wT[t] = convw[(c * 300 + e) * 5 + w];
}

// ---------------- contrib GEMM: 16 rows x 5 cols per thread, fp32 ----------------
__global__ __launch_bounds__(256) void k_contrib(const float* __restrict__ emb,
                                                 const float* __restrict__ wT,
                                                 float* __restrict__ contrib){
  __shared__ float aS[16][304];                // 19,456 B
  int tid = threadIdx.x;
  int v0 = blockIdx.x * 16;                    // 316 tiles -> v < 5056
  int cb = blockIdx.y * 1280 + tid;            // y in {0,1}; cols cb + j*256, j<5
  #pragma unroll
  for (int r = 0; r < 16; ++r){
    int v = v0 + r;
    for (int e = tid; e < 304; e += 256)
      aS[r][e] = (v < 5053 && e < 300) ? emb[(size_t)v * 300 + e] : 0.f;
  }
  __syncthreads();
  float acc[5][16];
  #pragma unroll
  for (int j = 0; j < 5; ++j)
    #pragma unroll
    for (int r = 0; r < 16; ++r) acc[j][r] = 0.f;
  for (int e = 0; e < 300; e += 4){
    float b0[5], b1[5], b2[5], b3[5];
    #pragma unroll
    for (int j = 0; j < 5; ++j){
      b0[j] = wT[(size_t)(e + 0) * 2560 + cb + j * 256];
      b1[j] = wT[(size_t)(e + 1) * 2560 + cb + j * 256];
      b2[j] = wT[(size_t)(e + 2) * 2560 + cb + j * 256];
      b3[j] = wT[(size_t)(e + 3) * 2560 + cb + j * 256];
    }
    #pragma unroll
    for (int r = 0; r < 16; ++r){
      float4 a = *(const float4*)&aS[r][e];
      #pragma unroll
      for (int j = 0; j < 5; ++j)
        acc[j][r] += a.x * b0[j] + a.y * b1[j] + a.z * b2[j] + a.w * b3[j];
    }
  }
  #pragma unroll
  for (int r = 0; r < 16; ++r){
    if (v0 + r < 5053){                        // never write the hole rows
      #pragma unroll
      for (int j = 0; j < 5; ++j)
        contrib[(size_t)(v0 + r) * 2560 + cb + j * 256] = acc[j][r];
    }
  }
}

// ---------------- char-CNN gather: one block per sequence; optional entity list ----------------
__global__ __launch_bounds__(256) void k_conv(const int* __restrict__ idx, int L,
                                              const float* __restrict__ contrib,
                                              const float* __restrict__ convb,
                                              float* __restrict__ featAll, int row0,
                                              const int* __restrict__ list,
                                              const int* __restrict__ nUsed){
  __shared__ int tok[128];
  __shared__ float4 red[256];
  int b = blockIdx.x, tid = threadIdx.x;
  int s = b;
  if (list){
    if (b >= *nUsed) return;
    s = list[b];
  }
  const int* row = idx + (size_t)s * L;
  for (int i = tid; i < L; i += 256) tok[i] = row[i];
  __syncthreads();
  int c4 = tid & 127;                 // channel quad -> 512 channels
  int ph = tid >> 7;                  // position-half 0/1
  float4 bias = *(const float4*)(convb + c4 * 4);
  float4 mx = {0.f, 0.f, 0.f, 0.f};   // relu floor folded into init
  int P = L - 4;
  int half = (P + 1) >> 1;
  int p = ph ? half : 0;
  int pe = ph ? P : half;
  for (; p + 1 < pe; p += 2){         // 2 positions/iter -> 10 loads in flight
    float4 a0 = bias, a1 = bias;
    #pragma unroll
    for (int w = 0; w < 5; ++w){
      float4 v0 = *(const float4*)(contrib + ((size_t)tok[p + w] * 5 + w) * 512 + c4 * 4);
      float4 v1 = *(const float4*)(contrib + ((size_t)tok[p + 1 + w] * 5 + w) * 512 + c4 * 4);
      a0.x += v0.x; a0.y += v0.y; a0.z += v0.z; a0.w += v0.w;
      a1.x += v1.x; a1.y += v1.y; a1.z += v1.z; a1.w += v1.w;
    }
    mx.x = fmaxf(mx.x, fmaxf(a0.x, a1.x)); mx.y = fmaxf(mx.y, fmaxf(a0.y, a1.y));
    mx.z = fmaxf(mx.z, fmaxf(a0.z, a1.z)); mx.w = fmaxf(mx.w, fmaxf(a0.w, a1.w));
  }
  if (p < pe){                        // odd tail
    float4 a0 = bias;
    #pragma unroll
    for (int w = 0; w < 5; ++w){
      float4 v0 = *(const float4*)(contrib + ((size_t)tok[p + w] * 5 + w) * 512 + c4 * 4);
      a0.x += v0.x; a0.y += v0.y; a0.z += v0.z; a0.w += v0.w;
    }
    mx.x = fmaxf(mx.x, a0.x); mx.y = fmaxf(mx.y, a0.y);
    mx.z = fmaxf(mx.z, a0.z); mx.w = fmaxf(mx.w, a0.w);
  }
  red[tid] = mx;
  __syncthreads();
  if (tid < 128){
    float4 a = red[tid], bb = red[tid + 128];
    a.x = fmaxf(a.x, bb.x); a.y = fmaxf(a.y, bb.y);
    a.z = fmaxf(a.z, bb.z); a.w = fmaxf(a.w, bb.w);
    *(float4*)(featAll + (size_t)(row0 + s) * 512 + c4 * 4) = a;
  }
}

// ---------------- doc conv: 32 blocks x 16 positions, atomicMax merge ----------------
__global__ __launch_bounds__(256) void k_conv_doc(const int* __restrict__ doc,
                                                  const float* __restrict__ contrib,
                                                  const float* __restrict__ convb,
                                                  float* __restrict__ featDoc){
  __shared__ int tok[512];
  __shared__ float4 red[256];
  int b = blockIdx.x, tid = threadIdx.x;
  for (int i = tid; i < 512; i += 256) tok[i] = doc[i];
  __syncthreads();
  int c4 = tid & 127, ph = tid >> 7;
  float4 bias = *(const float4*)(convb + c4 * 4);
  float4 mx = {0.f, 0.f, 0.f, 0.f};
  int p0 = b * 16, p1 = min(p0 + 16, 508);
  int n = p1 - p0, half = (n + 1) >> 1;
  int p = p0 + (ph ? half : 0);
  int pe = ph ? p1 : p0 + half;
  for (; p < pe; ++p){
    float4 a0 = bias;
    #pragma unroll
    for (int w = 0; w < 5; ++w){
      float4 v0 = *(const float4*)(contrib + ((size_t)tok[p + w] * 5 + w) * 512 + c4 * 4);
      a0.x += v0.x; a0.y += v0.y; a0.z += v0.z; a0.w += v0.w;
    }
    mx.x = fmaxf(mx.x, a0.x); mx.y = fmaxf(mx.y, a0.y);
    mx.z = fmaxf(mx.z, a0.z); mx.w = fmaxf(mx.w, a0.w);
  }
  red[tid] = mx;
  __syncthreads();
  if (tid < 128){
    float4 a = red[tid], bb = red[tid + 128];
    a.x = fmaxf(a.x, bb.x); a.y = fmaxf(a.y, bb.y);
    a.z = fmaxf(a.z, bb.z); a.w = fmaxf(a.w, bb.w);
    // values >= 0 -> IEEE order == int order
    atomicMax((int*)(featDoc + c4 * 4 + 0), __float_as_int(a.x));
    atomicMax((int*)(featDoc + c4 * 4 + 1), __float_as_int(a.y));
    atomicMax((int*)(featDoc + c4 * 4 + 2), __float_as_int(a.z));
    atomicMax((int*)(featDoc + c4 * 4 + 3), __float_as_int(a.w));
  }
}

// ---------------- repack Wih -> WihT[dir][k][col] ----------------
__global__ __launch_bounds__(256) void k_wihT(const float* __restrict__ Wf,
                                              const float* __restrict__ Wb,
                                              float* __restrict__ WihT){
  int t = blockIdx.x * 256 + threadIdx.x;      // < 2*512*512 = 524288
  int dir = t >> 18, r = t & 262143;
  int k = r >> 9, col = r & 511;
  WihT[t] = (dir ? Wb : Wf)[col * 512 + k];
}

// ---------------- input projection (fp32, 16 rows x 2 cols): preAll[dir][row][col] ----------------
__global__ __launch_bounds__(256) void k_proj(const float* __restrict__ featAll,
                                              const float* __restrict__ WihT,
                                              const float* __restrict__ bihF, const float* __restrict__ bhhF,
                                              const float* __restrict__ bihB, const float* __restrict__ bhhB,
                                              float* __restrict__ preAll){
  __shared__ float aS[16][516];                // 33,024 B
  int tid = threadIdx.x;
  int v0 = blockIdx.x * 16;                    // 261 tiles -> rows < 4176
  int dir = blockIdx.z;
  int col0 = tid, col1 = tid + 256;
  #pragma unroll
  for (int r = 0; r < 16; ++r)
    for (int k = tid; k < 516; k += 256)
      aS[r][k] = (k < 512) ? featAll[(size_t)(v0 + r) * 512 + k] : 0.f;
  __syncthreads();
  const float* BT = WihT + (size_t)dir * 262144;
  float acc0[16], acc1[16];
  #pragma unroll
  for (int r = 0; r < 16; ++r){ acc0[r] = 0.f; acc1[r] = 0.f; }
  for (int k = 0; k < 512; k += 4){
    float b00 = BT[(size_t)(k + 0) * 512 + col0];
    float b01 = BT[(size_t)(k + 1) * 512 + col0];
    float b02 = BT[(size_t)(k + 2) * 512 + col0];
    float b03 = BT[(size_t)(k + 3) * 512 + col0];
    float b10 = BT[(size_t)(k + 0) * 512 + col1];
    float b11 = BT[(size_t)(k + 1) * 512 + col1];
    float b12 = BT[(size_t)(k + 2) * 512 + col1];
    float b13 = BT[(size_t)(k + 3) * 512 + col1];
    #pragma unroll
    for (int r = 0; r < 16; ++r){
      float4 a = *(const float4*)&aS[r][k];
      acc0[r] += a.x * b00 + a.y * b01 + a.z * b02 + a.w * b03;
      acc1[r] += a.x * b10 + a.y * b11 + a.z * b12 + a.w * b13;
    }
  }
  float bias0 = (dir ? bihB : bihF)[col0] + (dir ? bhhB : bhhF)[col0];
  float bias1 = (dir ? bihB : bihF)[col1] + (dir ? bhhB : bhhF)[col1];
  float* outp = preAll + (size_t)dir * 4176 * 512;
  #pragma unroll
  for (int r = 0; r < 16; ++r){
    outp[(size_t)(v0 + r) * 512 + col0] = acc0[r] + bias0;
    outp[(size_t)(v0 + r) * 512 + col1] = acc1[r] + bias1;
  }
}

// ---------------- LSTM recurrence (fp64): block = one (chain, dir); 512 threads ----------------
__global__ __launch_bounds__(512) void k_recur(const float* __restrict__ preAll,
                                               const float* __restrict__ WhhF,
                                               const float* __restrict__ WhhB,
                                               const int* __restrict__ cand,
                                               double* __restrict__ hT, double* __restrict__ hB,
                                               double* __restrict__ hC, double* __restrict__ hD){
  int c = blockIdx.x, dir = blockIdx.y, tid = threadIdx.x;
  int lstm = (c < 64) ? 0 : (c < 128) ? 1 : (c < 192) ? 2 : 3;
  int b = (lstm == 3) ? 0 : (c - lstm * 64);
  const float* Whh = dir ? WhhB : WhhF;
  const float* pre = preAll + (size_t)dir * 4176 * 512;
  double* hout;
  if (lstm == 0)      hout = hT + (size_t)b * 32 * 256;
  else if (lstm == 1) hout = hB + (size_t)b * 32 * 256;
  else if (lstm == 2) hout = hC + (size_t)b * 32 * 256;
  else                hout = hD;
  hout += dir * 128;

  float wr[128];
  #pragma unroll
  for (int i = 0; i < 128; ++i) wr[i] = Whh[(size_t)tid * 128 + i];

  __shared__ double hs[128];
  __shared__ double gd[512];
  __shared__ int candL[32];
  if (tid < 128) hs[tid] = 0.0;
  if (lstm < 2 && tid < 32) candL[tid] = cand[b * 32 + tid];
  __syncthreads();
  double cst = 0.0;
  for (int s = 0; s < 32; ++s){
    int t = dir ? (31 - s) : s;
    int rowi;
    if (lstm == 0)      rowi = candL[t];
    else if (lstm == 1) rowi = 2048 + candL[t];
    else if (lstm == 2) rowi = 4096 + b;
    else                rowi = 4160;
    double g = (double)pre[(size_t)rowi * 512 + tid];
    #pragma unroll
    for (int j = 0; j < 128; ++j)
      g += (double)wr[j] * hs[j];
    gd[tid] = g;
    __syncthreads();
    if (tid < 128){
      double gi = gd[tid], gf = gd[tid + 128], gg = gd[tid + 256], go = gd[tid + 384];
      double si = 1.0 / (1.0 + exp(-gi));
      double sf = 1.0 / (1.0 + exp(-gf));
      double so = 1.0 / (1.0 + exp(-go));
      cst = sf * cst + si * tanh(gg);
      double h = so * tanh(cst);
      hs[tid] = h;
      hout[(size_t)t * 256 + tid] = h;
    }
    __syncthreads();
  }
}

// ---------------- BiDAF attention + scoring + scatter (fp64): one block per mention ----------------
__global__ __launch_bounds__(256) void k_att(const double* __restrict__ hC,
                                             const double* __restrict__ hT,
                                             const double* __restrict__ hD,
                                             const double* __restrict__ hB,
                                             const float* __restrict__ wc_g, const float* __restrict__ bc_g,
                                             const float* __restrict__ wq_g, const float* __restrict__ bq_g,
                                             const float* __restrict__ wcq_g, const float* __restrict__ bcq_g,
                                             const float* __restrict__ wz_g, const float* __restrict__ bz_g,
                                             const float* __restrict__ wp1_g, const float* __restrict__ bp1_g,
                                             const float* __restrict__ wp2_g, const float* __restrict__ bp2_g,
                                             const int* __restrict__ cand,
                                             float* __restrict__ out){
  int b = blockIdx.x, tid = threadIdx.x;
  __shared__ double sD[32][33];
  __shared__ double tD[32][33];
  __shared__ double cwS[32], qwS[32], qzS[32], smaxS[32], bsmS[32];
  __shared__ double q2cS[256];
  __shared__ double p1S[32], p2S[32], scoreS[32], redS[3];
  double bsum = (double)bc_g[0] + (double)bq_g[0] + (double)bcq_g[0];
  double bzv = (double)bz_g[0];
  double pa = 0.0;
  for (int pass = 0; pass < 2; ++pass){
    const double* cp = pass ? hD : (hC + (size_t)b * 8192);
    const double* qp = (pass ? hB : hT) + (size_t)b * 8192;
    if (tid < 32){
      double a = 0;
      for (int d = 0; d < 256; ++d) a += cp[(size_t)tid * 256 + d] * (double)wc_g[d];
      cwS[tid] = a;
    } else if (tid < 64){
      int j = tid - 32; double a = 0;
      for (int d = 0; d < 256; ++d) a += qp[(size_t)j * 256 + d] * (double)wq_g[d];
      qwS[j] = a;
    } else if (tid < 96){
      int j = tid - 64; double a = 0;
      for (int d = 0; d < 256; ++d) a += qp[(size_t)j * 256 + d] * (double)wz_g[256 + d];
      qzS[j] = a;
    }
    {
      int i = tid >> 3, js = tid & 7;
      double sa[4] = {0,0,0,0}, ta[4] = {0,0,0,0};
      for (int d = 0; d < 256; ++d){
        double cd = cp[(size_t)i * 256 + d];
        double cw1 = cd * (double)wcq_g[d];
        double cw2 = cd * (double)wz_g[512 + d];
        #pragma unroll
        for (int m = 0; m < 4; ++m){
          double qv = qp[(size_t)(js + m * 8) * 256 + d];
          sa[m] += cw1 * qv;
          ta[m] += cw2 * qv;
        }
      }
      __syncthreads();
      #pragma unroll
      for (int m = 0; m < 4; ++m){
        int j = js + m * 8;
        sD[i][j] = sa[m] + cwS[i] + qwS[j] + bsum;
        tD[i][j] = ta[m];
      }
    }
    __syncthreads();
    if (tid < 32){
      int i = tid;
      double mx = sD[i][0];
      for (int j = 1; j < 32; ++j) mx = fmax(mx, sD[i][j]);
      smaxS[i] = mx;
      double sum = 0, acc = 0;
      for (int j = 0; j < 32; ++j){
        double e = exp(sD[i][j] - mx);
        sum += e;
        acc += e * (qzS[j] + tD[i][j]);
      }
      pa = acc / sum;
    }
    __syncthreads();
    if (tid == 0){
      double mx = smaxS[0];
      for (int i = 1; i < 32; ++i) mx = fmax(mx, smaxS[i]);
      double sum = 0, e_[32];
      for (int i = 0; i < 32; ++i){ e_[i] = exp(smaxS[i] - mx); sum += e_[i]; }
      double inv = 1.0 / sum;
      for (int i = 0; i < 32; ++i) bsmS[i] = e_[i] * inv;
    }
    __syncthreads();
    {
      double a = 0;
      for (int i = 0; i < 32; ++i) a += bsmS[i] * cp[(size_t)i * 256 + tid];
      q2cS[tid] = a;
    }
    __syncthreads();
    if (tid < 32){
      int i = tid; double t1 = 0, t4 = 0;
      for (int d = 0; d < 256; ++d){
        double cd = cp[(size_t)i * 256 + d];
        t1 += cd * (double)wz_g[d];
        t4 += cd * q2cS[d] * (double)wz_g[768 + d];
      }
      double pv = t1 + pa + t4 + bzv;
      if (pass) p2S[i] = pv; else p1S[i] = pv;
    }
    __syncthreads();
  }
  if (tid < 32)
    scoreS[tid] = (double)wp1_g[0] * p1S[tid] + (double)bp1_g[0]
                + (double)wp2_g[0] * p2S[tid] + (double)bp2_g[0];
  __syncthreads();
  if (tid == 0){
    double mx = scoreS[0];
    for (int i = 1; i < 32; ++i) mx = fmax(mx, scoreS[i]);
    double es = 0, rs = 0;
    for (int i = 0; i < 32; ++i){ es += exp(scoreS[i] - mx); rs += scoreS[i]; }
    redS[0] = mx; redS[1] = es; redS[2] = rs;
  }
  __syncthreads();
  if (tid < 32){
    int col = cand[b * 32 + tid];
    double sc = scoreS[tid];
    out[(size_t)b * 2048 + col] = (float)sc;
    out[131072 + (size_t)b * 2048 + col] = (float)(exp(sc - redS[0]) / redS[1]);
    out[262144 + (size_t)b * 2048 + col] = (float)(sc / redS[2]);
  }
}

// ---------------------------------------------------------------------------
extern "C" void kernel_launch(void* const* d_in, const int* in_sizes, int n_in,
                              void* d_out, int out_size, void* d_ws, size_t ws_size,
                              hipStream_t stream) {
  const int* title_v = (const int*)d_in[0];
  const int* body_v  = (const int*)d_in[1];
  const int* ctx_v   = (const int*)d_in[3];
  const int* doc_v   = (const int*)d_in[4];
  const int* cand    = (const int*)d_in[5];
  const float* emb   = (const float*)d_in[6];
  const float* convw = (const float*)d_in[7];
  const float* convb = (const float*)d_in[8];
  const float* WihF  = (const float*)d_in[9];
  const float* WhhF  = (const float*)d_in[10];
  const float* bihF  = (const float*)d_in[11];
  const float* bhhF  = (const float*)d_in[12];
  const float* WihB  = (const float*)d_in[13];
  const float* WhhB  = (const float*)d_in[14];
  const float* bihB  = (const float*)d_in[15];
  const float* bhhB  = (const float*)d_in[16];
  float* out = (float*)d_out;

  const size_t CONTRIB_B = (size_t)5056 * 2560 * 4;     // 51,773,440
  const size_t FEAT_B    = (size_t)4176 * 512 * 4;      //  8,552,448
  char* base = (char*)d_ws;
  if (ws_size < CONTRIB_B + FEAT_B) return;
  float* contrib = (float*)base;
  char* featBase = base + CONTRIB_B;
  float* wT   = (float*)featBase;                       // dead before feat writes
  float* feat = (float*)featBase;
  float* featDoc = feat + (size_t)4160 * 512;

  // dedup buffers in the contrib hole (rows v>=5053, never read/written)
  int* flags = (int*)(base + HOLE_B);
  int* nUsed = (int*)(base + HOLE_B + 8192);
  int* list  = (int*)(base + HOLE_B + 8448);

  // post-conv aliases inside contrib
  float*  WihT   = (float*)(base);                      //  2,097,152 B
  float*  preAll = (float*)(base + 2097152);            // 17,104,896 B -> ends 19,202,048
  double* hT     = (double*)(base + 19202048);
  double* hB     = (double*)(base + 23396352);
  double* hC     = (double*)(base + 27590656);
  double* hD     = (double*)(base + 31784960);          // ends 31,850,496 < HOLE_B

  k_init<<<(out_size + 255) / 256, 256, 0, stream>>>((unsigned int*)out, out_size,
                                                     (unsigned int*)(base + HOLE_B), featDoc);
  k_mark<<<8, 256, 0, stream>>>(cand, flags);
  k_compact<<<8, 256, 0, stream>>>(flags, nUsed, list);
  k_wT<<<3000, 256, 0, stream>>>(convw, wT);
  k_contrib<<<dim3(316, 2), 256, 0, stream>>>(emb, wT, contrib);

  k_conv<<<2048, 256, 0, stream>>>(title_v, 32, contrib, convb, feat, 0, list, nUsed);
  k_conv<<<2048, 256, 0, stream>>>(body_v, 128, contrib, convb, feat, 2048, list, nUsed);
  k_conv<<<64, 256, 0, stream>>>(ctx_v, 128, contrib, convb, feat, 4096, (const int*)nullptr, (const int*)nullptr);
  k_conv_doc<<<32, 256, 0, stream>>>(doc_v, contrib, convb, featDoc);

  k_wihT<<<2048, 256, 0, stream>>>(WihF, WihB, WihT);
  k_proj<<<dim3(261, 1, 2), 256, 0, stream>>>(feat, WihT, bihF, bhhF, bihB, bhhB, preAll);
  k_recur<<<dim3(193, 2), 512, 0, stream>>>(preAll, WhhF, WhhB, cand, hT, hB, hC, hD);
  k_att<<<64, 256, 0, stream>>>(hC, hT, hD, hB,
                                (const float*)d_in[17], (const float*)d_in[18],
                                (const float*)d_in[19], (const float*)d_in[20],
                                (const float*)d_in[21], (const float*)d_in[22],
                                (const float*)d_in[23], (const float*)d_in[24],
                                (const float*)d_in[25], (const float*)d_in[26],
                                (const float*)d_in[27], (const float*)d_in[28],
                                cand, out);
}